// Round 1
// baseline (314.288 us; speedup 1.0000x reference)
//
#include <hip/hip_runtime.h>
#include <hip/hip_bf16.h>
#include <stdint.h>

#define E_IN_N   1048576
#define E_OUT_N  131072
#define KTAPS    9
#define CIN      64
#define COUT     64
#define NCELL    (E_OUT_N*KTAPS)   /* 1179648 */
#define NB_SCAN  1152              /* NCELL/1024 */
#define TILE_E   32
#define NKSTEP   18                /* 576/32 */

typedef __attribute__((ext_vector_type(8))) short bf16x8;
typedef __attribute__((ext_vector_type(4))) float f32x4;

__device__ __forceinline__ ushort f32_bf16(float x){
  union{float f; uint32_t u;} v; v.f=x;
  uint32_t r = v.u + 0x7FFFu + ((v.u>>16)&1u);
  return (ushort)(r>>16);
}

__global__ void hist_k(const int* __restrict__ seg, const int* __restrict__ succ,
                       int* __restrict__ counts){
  int i = blockIdx.x*256 + threadIdx.x;
  if (i < E_IN_N){ int cell = seg[i]*KTAPS + succ[i]; atomicAdd(&counts[cell],1); }
}

__global__ void blocksum_k(const int* __restrict__ counts, int* __restrict__ bsum){
  __shared__ int sm[256];
  int b=blockIdx.x, t=threadIdx.x;
  const int4 c4 = *(const int4*)(counts + b*1024 + t*4);
  int s=c4.x+c4.y+c4.z+c4.w;
  sm[t]=s; __syncthreads();
  for(int d=128; d>0; d>>=1){ if(t<d) sm[t]+=sm[t+d]; __syncthreads(); }
  if(t==0) bsum[b]=sm[0];
}

__global__ void scanb_k(const int* __restrict__ bsum, int* __restrict__ boff){
  __shared__ int sm[256];
  int t=threadIdx.x;
  int v[5]; int s=0;
  #pragma unroll
  for(int u=0;u<5;u++){ int idx=t*5+u; v[u]=(idx<NB_SCAN)?bsum[idx]:0; s+=v[u]; }
  sm[t]=s; __syncthreads();
  for(int d=1; d<256; d<<=1){ int x=(t>=d)?sm[t-d]:0; __syncthreads(); sm[t]+=x; __syncthreads(); }
  int excl=(t==0)?0:sm[t-1];
  #pragma unroll
  for(int u=0;u<5;u++){ int idx=t*5+u; if(idx<NB_SCAN) boff[idx]=excl; excl+=v[u]; }
}

__global__ void offsets_k(const int* __restrict__ counts, const int* __restrict__ boff,
                          int* __restrict__ offsets, int* __restrict__ cursor){
  __shared__ int sm[256];
  int b=blockIdx.x, t=threadIdx.x;
  int base=b*1024+t*4;
  const int4 c4=*(const int4*)(counts+base);
  int s=c4.x+c4.y+c4.z+c4.w;
  sm[t]=s; __syncthreads();
  for(int d=1; d<256; d<<=1){ int x=(t>=d)?sm[t-d]:0; __syncthreads(); sm[t]+=x; __syncthreads(); }
  int e0v=boff[b] + ((t==0)?0:sm[t-1]);
  int4 o; o.x=e0v; o.y=e0v+c4.x; o.z=o.y+c4.y; o.w=o.z+c4.z;
  *(int4*)(offsets+base)=o; *(int4*)(cursor+base)=o;
  if(b==NB_SCAN-1 && t==255) offsets[NCELL]=o.w+c4.w;
}

__global__ void scatter_k(const int* __restrict__ seg, const int* __restrict__ succ,
                          int* __restrict__ cursor, int* __restrict__ sorted){
  int i=blockIdx.x*256+threadIdx.x;
  if(i<E_IN_N){ int cell=seg[i]*KTAPS+succ[i]; int pos=atomicAdd(&cursor[cell],1); sorted[pos]=i; }
}

// pre-permute W[576][64] f32 -> bf16 MFMA B-fragment order: wb[((nt*18+ks)*64+lane)*8+j]
__global__ void wprep_k(const float* __restrict__ wk, ushort* __restrict__ wb){
  int slot=blockIdx.x*256+threadIdx.x;   // 36864 total
  int j=slot&7; int t2=slot>>3; int lane=t2&63; int t3=t2>>6;
  int ks=t3%NKSTEP; int nt=t3/NKSTEP;
  int r=ks*32+((lane>>4)*8)+j; int col=nt*16+(lane&15);
  wb[slot]=f32_bf16(wk[r*COUT+col]);
}

__global__ __launch_bounds__(512,4) void compute_k(
    const float* __restrict__ features, const float* __restrict__ dtv,
    const float* __restrict__ decay, const float* __restrict__ bias,
    const int* __restrict__ offsets, const int* __restrict__ sorted,
    const ushort* __restrict__ wb, float* __restrict__ out)
{
  __shared__ ushort agg[TILE_E*584];   // 576 + 8 pad per row (bank-conflict-free b128 reads)
  const int tid=threadIdx.x, wv=tid>>6, lane=tid&63;
  const int e0=blockIdx.x*TILE_E;

  for(int i=tid;i<TILE_E*584/2;i+=512) ((uint32_t*)agg)[i]=0u;
  float x=decay[lane];
  float rate=fmaxf(x,0.f)+log1pf(__expf(-fabsf(x)));   // softplus
  __syncthreads();

  // ---- aggregation: wave wv owns 36 contiguous cells (4 output events) ----
  {
    const int c0=e0*KTAPS+wv*36;
    int j=offsets[c0];
    const int eEnd=offsets[c0+36];
    int cell=c0, cend=offsets[c0+1];
    float num=0.f, den=0.f;
    while(j<eEnd){
      int nb=eEnd-j; if(nb>4)nb=4;
      int i0=sorted[j];
      int i1=(nb>1)?sorted[j+1]:i0;
      int i2=(nb>2)?sorted[j+2]:i0;
      int i3=(nb>3)?sorted[j+3]:i0;
      float d0=dtv[i0],d1=dtv[i1],d2=dtv[i2],d3=dtv[i3];
      float f0=features[(size_t)i0*CIN+lane];
      float f1=features[(size_t)i1*CIN+lane];
      float f2=features[(size_t)i2*CIN+lane];
      float f3=features[(size_t)i3*CIN+lane];
      float w0=__expf(-d0*rate),w1=__expf(-d1*rate),w2=__expf(-d2*rate),w3=__expf(-d3*rate);
      float ws_[4]={w0,w1,w2,w3}, fs_[4]={f0,f1,f2,f3};
      #pragma unroll
      for(int b=0;b<4;b++){
        if(b>=nb) break;
        while(j+b>=cend){
          if(den>0.f){
            int rel=cell-e0*KTAPS; int le=rel/KTAPS; int kk=rel-le*KTAPS;
            agg[le*584+kk*64+lane]=f32_bf16(num/den);
            num=0.f; den=0.f;
          }
          cell++; cend=offsets[cell+1];
        }
        num+=ws_[b]*fs_[b]; den+=ws_[b];
      }
      j+=nb;
    }
    if(den>0.f){
      int rel=cell-e0*KTAPS; int le=rel/KTAPS; int kk=rel-le*KTAPS;
      agg[le*584+kk*64+lane]=f32_bf16(num/den);
    }
  }
  __syncthreads();

  // ---- GEMM: wave tile = 16 rows (mt) x 16 cols (nt), K=576 ----
  const int mt=wv>>2, nt=wv&3;
  const int arow=mt*16+(lane&15);
  const int koff=(lane>>4)*8;
  const ushort* wbp = wb + ((size_t)(nt*NKSTEP)*64 + (size_t)lane)*8;
  f32x4 acc={0.f,0.f,0.f,0.f};
  #pragma unroll
  for(int ks=0;ks<NKSTEP;ks++){
    bf16x8 a=*(const bf16x8*)&agg[arow*584+ks*32+koff];
    bf16x8 bfr=*(const bf16x8*)(wbp + (size_t)ks*512);
    acc=__builtin_amdgcn_mfma_f32_16x16x32_bf16(a,bfr,acc,0,0,0);
  }
  const int orow=e0+mt*16+((lane>>4)*4);
  const int ocol=nt*16+(lane&15);
  const float bv=bias[ocol];
  #pragma unroll
  for(int r=0;r<4;r++) out[(size_t)(orow+r)*COUT+ocol]=acc[r]+bv;
}

extern "C" void kernel_launch(void* const* d_in, const int* in_sizes, int n_in,
                              void* d_out, int out_size, void* d_ws, size_t ws_size,
                              hipStream_t stream){
  const float* features=(const float*)d_in[0];
  const float* dtv=(const float*)d_in[1];
  const float* decay=(const float*)d_in[3];
  const float* wk=(const float*)d_in[4];
  const float* bias=(const float*)d_in[5];
  const int* succ=(const int*)d_in[6];
  const int* seg=(const int*)d_in[7];

  char* ws=(char*)d_ws;
  size_t o=0;
  int* counts=(int*)(ws+o);  o+=(size_t)NCELL*4;
  int* offsets=(int*)(ws+o); o+=(size_t)(NCELL+4)*4;
  int* cursor=(int*)(ws+o);  o+=(size_t)NCELL*4;
  int* bsum=(int*)(ws+o);    o+=(size_t)NB_SCAN*4;
  int* boff=(int*)(ws+o);    o+=(size_t)NB_SCAN*4;
  int* sorted=(int*)(ws+o);  o+=(size_t)E_IN_N*4;
  ushort* wb=(ushort*)(ws+o); o+=(size_t)36864*2;
  float* out=(float*)d_out;

  hipMemsetAsync(counts,0,(size_t)NCELL*4,stream);
  hipLaunchKernelGGL(hist_k, dim3(E_IN_N/256),dim3(256),0,stream, seg,succ,counts);
  hipLaunchKernelGGL(blocksum_k, dim3(NB_SCAN),dim3(256),0,stream, counts,bsum);
  hipLaunchKernelGGL(scanb_k, dim3(1),dim3(256),0,stream, bsum,boff);
  hipLaunchKernelGGL(offsets_k, dim3(NB_SCAN),dim3(256),0,stream, counts,boff,offsets,cursor);
  hipLaunchKernelGGL(scatter_k, dim3(E_IN_N/256),dim3(256),0,stream, seg,succ,cursor,sorted);
  hipLaunchKernelGGL(wprep_k, dim3(144),dim3(256),0,stream, wk,wb);
  hipLaunchKernelGGL(compute_k, dim3(E_OUT_N/TILE_E),dim3(512),0,stream,
                     features,dtv,decay,bias,offsets,sorted,wb,out);
}

// Round 2
// 244.377 us; speedup vs baseline: 1.2861x; 1.2861x over previous
//
#include <hip/hip_runtime.h>
#include <hip/hip_bf16.h>
#include <stdint.h>

#define E_IN_N   1048576
#define E_OUT_N  131072
#define KTAPS    9
#define CIN      64
#define COUT     64
#define NCELL    (E_OUT_N*KTAPS)   /* 1179648 */
#define NB_SCAN  1152              /* NCELL/1024 */
#define TILE_E   32
#define NKSTEP   18                /* 576/32 */

typedef __attribute__((ext_vector_type(8))) short bf16x8;
typedef __attribute__((ext_vector_type(4))) float f32x4;

__device__ __forceinline__ ushort f32_bf16(float x){
  union{float f; uint32_t u;} v; v.f=x;
  uint32_t r = v.u + 0x7FFFu + ((v.u>>16)&1u);
  return (ushort)(r>>16);
}

__global__ void hist_k(const int* __restrict__ seg, const int* __restrict__ succ,
                       int* __restrict__ counts){
  int i = blockIdx.x*256 + threadIdx.x;
  if (i < E_IN_N){ int cell = seg[i]*KTAPS + succ[i]; atomicAdd(&counts[cell],1); }
}

__global__ void blocksum_k(const int* __restrict__ counts, int* __restrict__ bsum){
  __shared__ int sm[256];
  int b=blockIdx.x, t=threadIdx.x;
  const int4 c4 = *(const int4*)(counts + b*1024 + t*4);
  int s=c4.x+c4.y+c4.z+c4.w;
  sm[t]=s; __syncthreads();
  for(int d=128; d>0; d>>=1){ if(t<d) sm[t]+=sm[t+d]; __syncthreads(); }
  if(t==0) bsum[b]=sm[0];
}

__global__ void scanb_k(const int* __restrict__ bsum, int* __restrict__ boff){
  __shared__ int sm[256];
  int t=threadIdx.x;
  int v[5]; int s=0;
  #pragma unroll
  for(int u=0;u<5;u++){ int idx=t*5+u; v[u]=(idx<NB_SCAN)?bsum[idx]:0; s+=v[u]; }
  sm[t]=s; __syncthreads();
  for(int d=1; d<256; d<<=1){ int x=(t>=d)?sm[t-d]:0; __syncthreads(); sm[t]+=x; __syncthreads(); }
  int excl=(t==0)?0:sm[t-1];
  #pragma unroll
  for(int u=0;u<5;u++){ int idx=t*5+u; if(idx<NB_SCAN) boff[idx]=excl; excl+=v[u]; }
}

__global__ void offsets_k(const int* __restrict__ counts, const int* __restrict__ boff,
                          int* __restrict__ offsets, int* __restrict__ cursor){
  __shared__ int sm[256];
  int b=blockIdx.x, t=threadIdx.x;
  int base=b*1024+t*4;
  const int4 c4=*(const int4*)(counts+base);
  int s=c4.x+c4.y+c4.z+c4.w;
  sm[t]=s; __syncthreads();
  for(int d=1; d<256; d<<=1){ int x=(t>=d)?sm[t-d]:0; __syncthreads(); sm[t]+=x; __syncthreads(); }
  int e0v=boff[b] + ((t==0)?0:sm[t-1]);
  int4 o; o.x=e0v; o.y=e0v+c4.x; o.z=o.y+c4.y; o.w=o.z+c4.z;
  *(int4*)(offsets+base)=o; *(int4*)(cursor+base)=o;
  if(b==NB_SCAN-1 && t==255) offsets[NCELL]=o.w+c4.w;
}

__global__ void scatter_k(const int* __restrict__ seg, const int* __restrict__ succ,
                          int* __restrict__ cursor, int* __restrict__ sorted){
  int i=blockIdx.x*256+threadIdx.x;
  if(i<E_IN_N){ int cell=seg[i]*KTAPS+succ[i]; int pos=atomicAdd(&cursor[cell],1); sorted[pos]=i; }
}

// pre-permute W[576][64] f32 -> bf16 MFMA B-fragment order: wb[((nt*18+ks)*64+lane)*8+j]
__global__ void wprep_k(const float* __restrict__ wk, ushort* __restrict__ wb){
  int slot=blockIdx.x*256+threadIdx.x;   // 36864 total
  int j=slot&7; int t2=slot>>3; int lane=t2&63; int t3=t2>>6;
  int ks=t3%NKSTEP; int nt=t3/NKSTEP;
  int r=ks*32+((lane>>4)*8)+j; int col=nt*16+(lane&15);
  wb[slot]=f32_bf16(wk[r*COUT+col]);
}

// Issue 8 feature-row loads (plus per-event dt via shfl) into buffer regs.
#define ISSUE(Fb,Db,bb) { \
  _Pragma("unroll") \
  for(int u=0;u<8;u++){ \
    int e=(bb)*8+u; int ec=(e<cn)?e:(cn-1); \
    int iu=__shfl(myIdx,ec); (Db)[u]=__shfl(myDt,ec); \
    (Fb)[u]=features[(size_t)iu*CIN+lane]; } }

// Consume 8 staged events: cell-walk (register offsets via shfl) + weighted merge.
#define CONSUME(Fb,Db,bb) { \
  _Pragma("unroll") \
  for(int u=0;u<8;u++){ \
    int e=(bb)*8+u; \
    if(e<cn){ \
      int jg=cb+e; \
      while(jg>=cend){ \
        if(den>0.f){ int rel=wv*36+cell; int le=rel/KTAPS; int kk=rel-le*KTAPS; \
          agg[le*584+kk*64+lane]=f32_bf16(num/den); num=0.f; den=0.f; } \
        cell++; cend=__shfl(offReg,cell+1); } \
      float w=__expf(-(Db)[u]*rate); \
      num=fmaf(w,(Fb)[u],num); den+=w; } } }

__global__ __launch_bounds__(512,4) void compute_k(
    const float* __restrict__ features, const float* __restrict__ dtv,
    const float* __restrict__ decay, const float* __restrict__ bias,
    const int* __restrict__ offsets, const int* __restrict__ sorted,
    const ushort* __restrict__ wb, float* __restrict__ out)
{
  __shared__ ushort agg[TILE_E*584];   // 576 + 8 pad per row
  const int tid=threadIdx.x, wv=tid>>6, lane=tid&63;
  const int e0=blockIdx.x*TILE_E;

  // each wave zero-inits ITS OWN 4 agg rows (no barrier needed before flushes)
  {
    uint32_t* z=(uint32_t*)agg + wv*1168;   // 4 rows * 584 ushort = 1168 uints
    #pragma unroll
    for(int i=0;i<18;i++) z[i*64+lane]=0u;
    if(lane<16) z[18*64+lane]=0u;           // 1168 = 18*64 + 16
  }
  float x=decay[lane];
  float rate=fmaxf(x,0.f)+log1pf(__expf(-fabsf(x)));   // softplus

  // ---- aggregation: wave wv owns 36 contiguous cells (4 output events) ----
  {
    const int c0=e0*KTAPS+wv*36;
    const int offIdx=(lane<=36)?lane:36;
    const int offReg=offsets[c0+offIdx];          // one coalesced load: all 37 offsets in regs
    const int j0=__shfl(offReg,0);
    const int jEnd=__shfl(offReg,36);

    int cell=0;
    int cend=__shfl(offReg,1);
    float num=0.f, den=0.f;

    for(int cb=j0; cb<jEnd; cb+=64){
      const int cn=min(64,jEnd-cb);
      int myIdx=0;
      if(lane<cn) myIdx=sorted[cb+lane];          // one coalesced load
      float myDt=dtv[myIdx];                      // one gather
      const int nb=(cn+7)>>3;
      float Af[8],Ad[8],Bf[8],Bd[8];
      ISSUE(Af,Ad,0)
      if(nb>1) ISSUE(Bf,Bd,1)
      CONSUME(Af,Ad,0)
      if(nb>2) ISSUE(Af,Ad,2)
      if(nb>1) CONSUME(Bf,Bd,1)
      if(nb>3) ISSUE(Bf,Bd,3)
      if(nb>2) CONSUME(Af,Ad,2)
      if(nb>4) ISSUE(Af,Ad,4)
      if(nb>3) CONSUME(Bf,Bd,3)
      if(nb>5) ISSUE(Bf,Bd,5)
      if(nb>4) CONSUME(Af,Ad,4)
      if(nb>6) ISSUE(Af,Ad,6)
      if(nb>5) CONSUME(Bf,Bd,5)
      if(nb>7) ISSUE(Bf,Bd,7)
      if(nb>6) CONSUME(Af,Ad,6)
      if(nb>7) CONSUME(Bf,Bd,7)
    }
    if(den>0.f){ int rel=wv*36+cell; int le=rel/KTAPS; int kk=rel-le*KTAPS;
      agg[le*584+kk*64+lane]=f32_bf16(num/den); }
  }
  __syncthreads();

  // ---- GEMM: wave tile = 16 rows (mt) x 16 cols (nt), K=576 ----
  const int mt=wv>>2, nt=wv&3;
  const int arow=mt*16+(lane&15);
  const int koff=(lane>>4)*8;
  const ushort* wbp = wb + ((size_t)(nt*NKSTEP)*64 + (size_t)lane)*8;
  f32x4 acc={0.f,0.f,0.f,0.f};
  #pragma unroll
  for(int ks=0;ks<NKSTEP;ks++){
    bf16x8 a=*(const bf16x8*)&agg[arow*584+ks*32+koff];
    bf16x8 bfr=*(const bf16x8*)(wbp + (size_t)ks*512);
    acc=__builtin_amdgcn_mfma_f32_16x16x32_bf16(a,bfr,acc,0,0,0);
  }
  const int orow=e0+mt*16+((lane>>4)*4);
  const int ocol=nt*16+(lane&15);
  const float bv=bias[ocol];
  #pragma unroll
  for(int r=0;r<4;r++) out[(size_t)(orow+r)*COUT+ocol]=acc[r]+bv;
}

extern "C" void kernel_launch(void* const* d_in, const int* in_sizes, int n_in,
                              void* d_out, int out_size, void* d_ws, size_t ws_size,
                              hipStream_t stream){
  const float* features=(const float*)d_in[0];
  const float* dtv=(const float*)d_in[1];
  const float* decay=(const float*)d_in[3];
  const float* wk=(const float*)d_in[4];
  const float* bias=(const float*)d_in[5];
  const int* succ=(const int*)d_in[6];
  const int* seg=(const int*)d_in[7];

  char* ws=(char*)d_ws;
  size_t o=0;
  int* counts=(int*)(ws+o);  o+=(size_t)NCELL*4;
  int* offsets=(int*)(ws+o); o+=(size_t)(NCELL+4)*4;
  int* cursor=(int*)(ws+o);  o+=(size_t)NCELL*4;
  int* bsum=(int*)(ws+o);    o+=(size_t)NB_SCAN*4;
  int* boff=(int*)(ws+o);    o+=(size_t)NB_SCAN*4;
  int* sorted=(int*)(ws+o);  o+=(size_t)E_IN_N*4;
  ushort* wb=(ushort*)(ws+o); o+=(size_t)36864*2;
  float* out=(float*)d_out;

  hipMemsetAsync(counts,0,(size_t)NCELL*4,stream);
  hipLaunchKernelGGL(hist_k, dim3(E_IN_N/256),dim3(256),0,stream, seg,succ,counts);
  hipLaunchKernelGGL(blocksum_k, dim3(NB_SCAN),dim3(256),0,stream, counts,bsum);
  hipLaunchKernelGGL(scanb_k, dim3(1),dim3(256),0,stream, bsum,boff);
  hipLaunchKernelGGL(offsets_k, dim3(NB_SCAN),dim3(256),0,stream, counts,boff,offsets,cursor);
  hipLaunchKernelGGL(scatter_k, dim3(E_IN_N/256),dim3(256),0,stream, seg,succ,cursor,sorted);
  hipLaunchKernelGGL(wprep_k, dim3(144),dim3(256),0,stream, wk,wb);
  hipLaunchKernelGGL(compute_k, dim3(E_OUT_N/TILE_E),dim3(512),0,stream,
                     features,dtv,decay,bias,offsets,sorted,wb,out);
}

// Round 3
// 238.703 us; speedup vs baseline: 1.3167x; 1.0238x over previous
//
#include <hip/hip_runtime.h>
#include <hip/hip_bf16.h>
#include <stdint.h>

#define E_IN_N   1048576
#define E_OUT_N  131072
#define KTAPS    9
#define CIN      64
#define COUT     64
#define NCELL    (E_OUT_N*KTAPS)   /* 1179648 */
#define NB_SCAN  1152              /* NCELL/1024 */
#define TILE_E   32
#define NKSTEP   18                /* 576/32 */
#define NUNITS   16                /* units per block, 2 output events each */

typedef __attribute__((ext_vector_type(8))) short bf16x8;
typedef __attribute__((ext_vector_type(4))) float f32x4;

__device__ __forceinline__ ushort f32_bf16(float x){
  union{float f; uint32_t u;} v; v.f=x;
  uint32_t r = v.u + 0x7FFFu + ((v.u>>16)&1u);
  return (ushort)(r>>16);
}

__global__ void zero_k(int* __restrict__ p){   // zero counts (NCELL ints)
  int i = blockIdx.x*256 + threadIdx.x;
  ((int4*)p)[i] = int4{0,0,0,0};               // NCELL/4 int4s = 294912
}

__global__ void hist_k(const int* __restrict__ seg, const int* __restrict__ succ,
                       int* __restrict__ counts, int* __restrict__ cells){
  int i = blockIdx.x*256 + threadIdx.x;
  int cell = seg[i]*KTAPS + succ[i];
  cells[i] = cell;
  atomicAdd(&counts[cell],1);
}

__global__ void blocksum_k(const int* __restrict__ counts, int* __restrict__ bsum){
  __shared__ int sm[256];
  int b=blockIdx.x, t=threadIdx.x;
  const int4 c4 = *(const int4*)(counts + b*1024 + t*4);
  int s=c4.x+c4.y+c4.z+c4.w;
  sm[t]=s; __syncthreads();
  for(int d=128; d>0; d>>=1){ if(t<d) sm[t]+=sm[t+d]; __syncthreads(); }
  if(t==0) bsum[b]=sm[0];
}

__global__ void scanb_k(const int* __restrict__ bsum, int* __restrict__ boff){
  __shared__ int sm[256];
  int t=threadIdx.x;
  int v[5]; int s=0;
  #pragma unroll
  for(int u=0;u<5;u++){ int idx=t*5+u; v[u]=(idx<NB_SCAN)?bsum[idx]:0; s+=v[u]; }
  sm[t]=s; __syncthreads();
  for(int d=1; d<256; d<<=1){ int x=(t>=d)?sm[t-d]:0; __syncthreads(); sm[t]+=x; __syncthreads(); }
  int excl=(t==0)?0:sm[t-1];
  #pragma unroll
  for(int u=0;u<5;u++){ int idx=t*5+u; if(idx<NB_SCAN) boff[idx]=excl; excl+=v[u]; }
}

__global__ void offsets_k(const int* __restrict__ counts, const int* __restrict__ boff,
                          int* __restrict__ offsets, int* __restrict__ cursor){
  __shared__ int sm[256];
  int b=blockIdx.x, t=threadIdx.x;
  int base=b*1024+t*4;
  const int4 c4=*(const int4*)(counts+base);
  int s=c4.x+c4.y+c4.z+c4.w;
  sm[t]=s; __syncthreads();
  for(int d=1; d<256; d<<=1){ int x=(t>=d)?sm[t-d]:0; __syncthreads(); sm[t]+=x; __syncthreads(); }
  int e0v=boff[b] + ((t==0)?0:sm[t-1]);
  int4 o; o.x=e0v; o.y=e0v+c4.x; o.z=o.y+c4.y; o.w=o.z+c4.z;
  *(int4*)(offsets+base)=o; *(int4*)(cursor+base)=o;
  if(b==NB_SCAN-1 && t==255) offsets[NCELL]=o.w+c4.w;
}

__global__ void scatter_k(const int* __restrict__ cells, const float* __restrict__ dtv,
                          int* __restrict__ cursor, int2* __restrict__ sorted2){
  int i=blockIdx.x*256+threadIdx.x;
  int cell=cells[i];
  float d=dtv[i];
  int pos=atomicAdd(&cursor[cell],1);
  sorted2[pos]=int2{i,__float_as_int(d)};
}

// pre-permute W[576][64] f32 -> bf16 MFMA B-fragment order: wb[((nt*18+ks)*64+lane)*8+j]
__global__ void wprep_k(const float* __restrict__ wk, ushort* __restrict__ wb){
  int slot=blockIdx.x*256+threadIdx.x;   // 36864 total
  int j=slot&7; int t2=slot>>3; int lane=t2&63; int t3=t2>>6;
  int ks=t3%NKSTEP; int nt=t3/NKSTEP;
  int r=ks*32+((lane>>4)*8)+j; int col=nt*16+(lane&15);
  wb[slot]=f32_bf16(wk[r*COUT+col]);
}

// Issue 8 feature-row loads (idx/dt broadcast via shfl) into buffer regs.
#define ISSUE(Fb,Db,bb) { \
  _Pragma("unroll") \
  for(int u=0;u<8;u++){ \
    int e=(bb)*8+u; int ec=(e<cn)?e:(cn-1); \
    int iu=__shfl(myIdx,ec); (Db)[u]=__shfl(myDt,ec); \
    (Fb)[u]=features[(size_t)iu*CIN+lane]; } }

// Consume 8 staged events: cell-walk (register offsets via shfl) + weighted merge.
#define CONSUME(Fb,Db,bb) { \
  _Pragma("unroll") \
  for(int u=0;u<8;u++){ \
    int e=(bb)*8+u; \
    if(e<cn){ \
      int jg=cb+e; \
      while(jg>=cend){ \
        if(den>0.f){ int le=uo2+(cell>=KTAPS); int kk=cell-((cell>=KTAPS)?KTAPS:0); \
          agg[le*584+kk*64+lane]=f32_bf16(num/den); num=0.f; den=0.f; } \
        cell++; cend=__shfl(offReg,cell+1); } \
      float w=__expf(-(Db)[u]*rate); \
      num=fmaf(w,(Fb)[u],num); den+=w; } } }

__global__ __launch_bounds__(512,4) void compute_k(
    const float* __restrict__ features, const float* __restrict__ decay,
    const float* __restrict__ bias, const int* __restrict__ offsets,
    const int2* __restrict__ sorted2, const ushort* __restrict__ wb,
    float* __restrict__ out)
{
  __shared__ ushort agg[TILE_E*584];   // 576 + 8 pad per row
  __shared__ int ctr;
  const int tid=threadIdx.x, wv=tid>>6, lane=tid&63;
  const int e0=blockIdx.x*TILE_E;
  const int cb0=e0*KTAPS;              // first cell of block

  // zero the whole agg tile + init steal counter, then one barrier
  for(int i=tid;i<TILE_E*584/2;i+=512) ((uint32_t*)agg)[i]=0u;
  if(tid==0) ctr=0;
  float x=decay[lane];
  float rate=fmaxf(x,0.f)+log1pf(__expf(-fabsf(x)));   // softplus
  __syncthreads();

  // ---- aggregation: waves steal 2-output-event units (18 cells), steal-ahead pipelined ----
  {
    const int offIdx=(lane<=18)?lane:18;
    int u; if(lane==0) u=atomicAdd(&ctr,1); u=__shfl(u,0);
    int offReg=(u<NUNITS)?offsets[cb0+u*18+offIdx]:0;

    while(u<NUNITS){
      // steal-ahead: grab next unit + issue its offsets load now
      int u2; if(lane==0) u2=atomicAdd(&ctr,1); u2=__shfl(u2,0);
      int offReg2=(u2<NUNITS)?offsets[cb0+u2*18+offIdx]:0;

      const int uo2=u*2;                       // first agg row of this unit
      const int j0=__shfl(offReg,0);
      const int jEnd=__shfl(offReg,18);
      int cell=0;
      int cend=__shfl(offReg,1);
      float num=0.f, den=0.f;

      for(int cb=j0; cb<jEnd; cb+=64){
        const int cn=min(64,jEnd-cb);
        int myIdx=0; float myDt=0.f;
        if(lane<cn){ int2 p=sorted2[cb+lane]; myIdx=p.x; myDt=__int_as_float(p.y); }
        const int nb=(cn+7)>>3;
        float Af[8],Ad[8],Bf[8],Bd[8];
        ISSUE(Af,Ad,0)
        if(nb>1) ISSUE(Bf,Bd,1)
        CONSUME(Af,Ad,0)
        if(nb>2) ISSUE(Af,Ad,2)
        if(nb>1) CONSUME(Bf,Bd,1)
        if(nb>3) ISSUE(Bf,Bd,3)
        if(nb>2) CONSUME(Af,Ad,2)
        if(nb>4) ISSUE(Af,Ad,4)
        if(nb>3) CONSUME(Bf,Bd,3)
        if(nb>5) ISSUE(Bf,Bd,5)
        if(nb>4) CONSUME(Af,Ad,4)
        if(nb>6) ISSUE(Af,Ad,6)
        if(nb>5) CONSUME(Bf,Bd,5)
        if(nb>7) ISSUE(Bf,Bd,7)
        if(nb>6) CONSUME(Af,Ad,6)
        if(nb>7) CONSUME(Bf,Bd,7)
      }
      if(den>0.f){ int le=uo2+(cell>=KTAPS); int kk=cell-((cell>=KTAPS)?KTAPS:0);
        agg[le*584+kk*64+lane]=f32_bf16(num/den); }

      u=u2; offReg=offReg2;
    }
  }
  __syncthreads();

  // ---- GEMM: wave tile = 16 rows (mt) x 16 cols (nt), K=576 ----
  const int mt=wv>>2, nt=wv&3;
  const int arow=mt*16+(lane&15);
  const int koff=(lane>>4)*8;
  const ushort* wbp = wb + ((size_t)(nt*NKSTEP)*64 + (size_t)lane)*8;
  f32x4 acc={0.f,0.f,0.f,0.f};
  #pragma unroll
  for(int ks=0;ks<NKSTEP;ks++){
    bf16x8 a=*(const bf16x8*)&agg[arow*584+ks*32+koff];
    bf16x8 bfr=*(const bf16x8*)(wbp + (size_t)ks*512);
    acc=__builtin_amdgcn_mfma_f32_16x16x32_bf16(a,bfr,acc,0,0,0);
  }
  const int orow=e0+mt*16+((lane>>4)*4);
  const int ocol=nt*16+(lane&15);
  const float bv=bias[ocol];
  #pragma unroll
  for(int r=0;r<4;r++) out[(size_t)(orow+r)*COUT+ocol]=acc[r]+bv;
}

extern "C" void kernel_launch(void* const* d_in, const int* in_sizes, int n_in,
                              void* d_out, int out_size, void* d_ws, size_t ws_size,
                              hipStream_t stream){
  const float* features=(const float*)d_in[0];
  const float* dtv=(const float*)d_in[1];
  const float* decay=(const float*)d_in[3];
  const float* wk=(const float*)d_in[4];
  const float* bias=(const float*)d_in[5];
  const int* succ=(const int*)d_in[6];
  const int* seg=(const int*)d_in[7];

  char* ws=(char*)d_ws;
  size_t o=0;
  int* counts=(int*)(ws+o);  o+=(size_t)NCELL*4;
  int* offsets=(int*)(ws+o); o+=(size_t)(NCELL+4)*4;
  int* cursor=(int*)(ws+o);  o+=(size_t)NCELL*4;
  int* bsum=(int*)(ws+o);    o+=(size_t)NB_SCAN*4;
  int* boff=(int*)(ws+o);    o+=(size_t)NB_SCAN*4;
  int* cells=(int*)(ws+o);   o+=(size_t)E_IN_N*4;
  int2* sorted2=(int2*)(ws+o); o+=(size_t)E_IN_N*8;
  ushort* wb=(ushort*)(ws+o); o+=(size_t)36864*2;
  float* out=(float*)d_out;

  hipLaunchKernelGGL(zero_k, dim3(NCELL/1024),dim3(256),0,stream, counts);
  hipLaunchKernelGGL(hist_k, dim3(E_IN_N/256),dim3(256),0,stream, seg,succ,counts,cells);
  hipLaunchKernelGGL(blocksum_k, dim3(NB_SCAN),dim3(256),0,stream, counts,bsum);
  hipLaunchKernelGGL(scanb_k, dim3(1),dim3(256),0,stream, bsum,boff);
  hipLaunchKernelGGL(offsets_k, dim3(NB_SCAN),dim3(256),0,stream, counts,boff,offsets,cursor);
  hipLaunchKernelGGL(scatter_k, dim3(E_IN_N/256),dim3(256),0,stream, cells,dtv,cursor,sorted2);
  hipLaunchKernelGGL(wprep_k, dim3(144),dim3(256),0,stream, wk,wb);
  hipLaunchKernelGGL(compute_k, dim3(E_OUT_N/TILE_E),dim3(512),0,stream,
                     features,decay,bias,offsets,sorted2,wb,out);
}

// Round 4
// 210.188 us; speedup vs baseline: 1.4953x; 1.1357x over previous
//
#include <hip/hip_runtime.h>
#include <hip/hip_bf16.h>
#include <stdint.h>

#define E_IN_N   1048576
#define E_OUT_N  131072
#define KTAPS    9
#define CIN      64
#define COUT     64
#define NCELL    (E_OUT_N*KTAPS)   /* 1179648 */
#define NB_SCAN  1152              /* NCELL/1024 */
#define TILE_E   32
#define NKSTEP   18                /* 576/32 */

typedef __attribute__((ext_vector_type(8))) short bf16x8;
typedef __attribute__((ext_vector_type(4))) float f32x4;

__device__ __forceinline__ ushort f32_bf16(float x){
  union{float f; uint32_t u;} v; v.f=x;
  uint32_t r = v.u + 0x7FFFu + ((v.u>>16)&1u);
  return (ushort)(r>>16);
}

__global__ void zero_k(int* __restrict__ p){   // zero counts (NCELL ints)
  int i = blockIdx.x*256 + threadIdx.x;
  ((int4*)p)[i] = int4{0,0,0,0};
}

// histogram + per-event rank; cellrank = cell<<11 | rank  (cell<2^21, rank<2048)
__global__ void hist_k(const int* __restrict__ seg, const int* __restrict__ succ,
                       int* __restrict__ counts, uint32_t* __restrict__ cellrank){
  int i = blockIdx.x*256 + threadIdx.x;
  uint32_t cell = (uint32_t)(seg[i]*KTAPS + succ[i]);
  uint32_t rank = (uint32_t)atomicAdd(&counts[cell],1);
  cellrank[i] = (cell<<11) | rank;
}

__global__ void blocksum_k(const int* __restrict__ counts, int* __restrict__ bsum){
  __shared__ int sm[256];
  int b=blockIdx.x, t=threadIdx.x;
  const int4 c4 = *(const int4*)(counts + b*1024 + t*4);
  int s=c4.x+c4.y+c4.z+c4.w;
  sm[t]=s; __syncthreads();
  for(int d=128; d>0; d>>=1){ if(t<d) sm[t]+=sm[t+d]; __syncthreads(); }
  if(t==0) bsum[b]=sm[0];
}

// fused: block prefix over bsum + intra-block scan of counts -> offsets
__global__ void offsets_k(const int* __restrict__ counts, const int* __restrict__ bsum,
                          int* __restrict__ offsets){
  __shared__ int sm[256];
  int b=blockIdx.x, t=threadIdx.x;
  // prefix of bsum[0..b)
  int s=0;
  for(int j=t; j<NB_SCAN; j+=256) if(j<b) s+=bsum[j];
  sm[t]=s; __syncthreads();
  for(int d=128; d>0; d>>=1){ if(t<d) sm[t]+=sm[t+d]; __syncthreads(); }
  int base0=sm[0]; __syncthreads();
  // intra-block inclusive scan of 4-sums
  int base=b*1024+t*4;
  const int4 c4=*(const int4*)(counts+base);
  int s2=c4.x+c4.y+c4.z+c4.w;
  sm[t]=s2; __syncthreads();
  for(int d=1; d<256; d<<=1){ int x=(t>=d)?sm[t-d]:0; __syncthreads(); sm[t]+=x; __syncthreads(); }
  int e0v=base0 + ((t==0)?0:sm[t-1]);
  int4 o; o.x=e0v; o.y=e0v+c4.x; o.z=o.y+c4.y; o.w=o.z+c4.z;
  *(int4*)(offsets+base)=o;
  if(b==NB_SCAN-1 && t==255) offsets[NCELL]=o.w+c4.w;
}

// place events: pos = offsets[cell] + rank (no atomics); payload = idx|(cell%288)<<20, dt
__global__ void scatter_k(const uint32_t* __restrict__ cellrank, const float* __restrict__ dtv,
                          const int* __restrict__ offsets, int2* __restrict__ sorted2){
  int i=blockIdx.x*256+threadIdx.x;
  uint32_t cr=cellrank[i];
  uint32_t cell=cr>>11, rank=cr&2047u;
  int base=offsets[cell];
  float d=dtv[i];
  uint32_t x=cell>>5;                         // /32
  uint32_t q=__umulhi(x,477218592u);          // /9  (exact for x<2^27)
  uint32_t rel=cell - q*288u;                 // cell % 288 (block-local)
  sorted2[base+(int)rank]=int2{(int)((uint32_t)i | (rel<<20)), __float_as_int(d)};
}

// pre-permute W[576][64] f32 -> bf16 MFMA B-fragment order: wb[((nt*18+ks)*64+lane)*8+j]
__global__ void wprep_k(const float* __restrict__ wk, ushort* __restrict__ wb){
  int slot=blockIdx.x*256+threadIdx.x;   // 36864 total
  int j=slot&7; int t2=slot>>3; int lane=t2&63; int t3=t2>>6;
  int ks=t3%NKSTEP; int nt=t3/NKSTEP;
  int r=ks*32+((lane>>4)*8)+j; int col=nt*16+(lane&15);
  wb[slot]=f32_bf16(wk[r*COUT+col]);
}

// Issue 8 feature-row loads (idx broadcast via shfl of packed word).
#define ISSUE(Fb,bb) { \
  _Pragma("unroll") \
  for(int u=0;u<8;u++){ \
    int e=(bb)*8+u; int ec=(e<cn)?e:(cn-1); \
    int iu=__shfl(pw,ec)&0xFFFFF; \
    (Fb)[u]=features[((size_t)iu<<6)+lane]; } }

#define FLUSH { int le=(curRel*7282)>>16; int kk=curRel-le*9; \
  float rr=__builtin_amdgcn_rcpf(den); \
  agg[le*584+kk*64+lane]=f32_bf16(num*rr); }

// Consume 8 staged events: flush on rel-change (empty cells never visited).
#define CONSUME(Fb,bb) { \
  _Pragma("unroll") \
  for(int u=0;u<8;u++){ \
    int e=(bb)*8+u; \
    if(e<cn){ \
      int r_=__shfl(pw,e)>>20; float d_=__shfl(pd,e); \
      if(r_!=curRel){ \
        if(curRel>=0){ FLUSH } \
        curRel=r_; num=0.f; den=0.f; } \
      float w=__expf(-d_*rate); \
      num=fmaf(w,(Fb)[u],num); den+=w; } } }

__global__ __launch_bounds__(512,4) void compute_k(
    const float* __restrict__ features, const float* __restrict__ decay,
    const float* __restrict__ bias, const int* __restrict__ offsets,
    const int2* __restrict__ sorted2, const ushort* __restrict__ wb,
    float* __restrict__ out)
{
  __shared__ ushort agg[TILE_E*584];   // 576 + 8 pad per row
  const int tid=threadIdx.x, wv=tid>>6, lane=tid&63;
  const int e0=blockIdx.x*TILE_E;
  const int cb0=e0*KTAPS;

  for(int i=tid;i<TILE_E*584/2;i+=512) ((uint32_t*)agg)[i]=0u;
  float x=decay[lane];
  float rate=fmaxf(x,0.f)+log1pf(__expf(-fabsf(x)));   // softplus
  __syncthreads();

  // ---- aggregation: wave owns 36 contiguous cells; payload carries rel ----
  {
    const int c0=cb0+wv*36;
    int jv=0; if(lane<2) jv=offsets[c0+lane*36];
    const int j0=__shfl(jv,0), jEnd=__shfl(jv,1);
    int curRel=-1; float num=0.f, den=0.f;

    if(j0<jEnd){
      int2 P=sorted2[min(j0+lane,jEnd-1)];
      for(int cb=j0; cb<jEnd; cb+=64){
        const int cn=min(64,jEnd-cb);
        int nx=cb+64+lane;
        int2 Pn=sorted2[(nx<jEnd)?nx:(jEnd-1)];   // prefetch next chunk
        const int pw=P.x; const float pd=__int_as_float(P.y);
        const int nb=(cn+7)>>3;
        float Af[8],Bf[8];
        ISSUE(Af,0)
        if(nb>1) ISSUE(Bf,1)
        CONSUME(Af,0)
        if(nb>2) ISSUE(Af,2)
        if(nb>1) CONSUME(Bf,1)
        if(nb>3) ISSUE(Bf,3)
        if(nb>2) CONSUME(Af,2)
        if(nb>4) ISSUE(Af,4)
        if(nb>3) CONSUME(Bf,3)
        if(nb>5) ISSUE(Bf,5)
        if(nb>4) CONSUME(Af,4)
        if(nb>6) ISSUE(Af,6)
        if(nb>5) CONSUME(Bf,5)
        if(nb>7) ISSUE(Bf,7)
        if(nb>6) CONSUME(Af,6)
        if(nb>7) CONSUME(Bf,7)
        P=Pn;
      }
      if(curRel>=0){ FLUSH }
    }
  }
  __syncthreads();

  // ---- GEMM: wave tile = 16 rows (mt) x 16 cols (nt), K=576 ----
  const int mt=wv>>2, nt=wv&3;
  const int arow=mt*16+(lane&15);
  const int koff=(lane>>4)*8;
  const ushort* wbp = wb + ((size_t)(nt*NKSTEP)*64 + (size_t)lane)*8;
  f32x4 acc={0.f,0.f,0.f,0.f};
  #pragma unroll
  for(int ks=0;ks<NKSTEP;ks++){
    bf16x8 a=*(const bf16x8*)&agg[arow*584+ks*32+koff];
    bf16x8 bfr=*(const bf16x8*)(wbp + (size_t)ks*512);
    acc=__builtin_amdgcn_mfma_f32_16x16x32_bf16(a,bfr,acc,0,0,0);
  }
  const int orow=e0+mt*16+((lane>>4)*4);
  const int ocol=nt*16+(lane&15);
  const float bv=bias[ocol];
  #pragma unroll
  for(int r=0;r<4;r++) out[(size_t)(orow+r)*COUT+ocol]=acc[r]+bv;
}

extern "C" void kernel_launch(void* const* d_in, const int* in_sizes, int n_in,
                              void* d_out, int out_size, void* d_ws, size_t ws_size,
                              hipStream_t stream){
  const float* features=(const float*)d_in[0];
  const float* dtv=(const float*)d_in[1];
  const float* decay=(const float*)d_in[3];
  const float* wk=(const float*)d_in[4];
  const float* bias=(const float*)d_in[5];
  const int* succ=(const int*)d_in[6];
  const int* seg=(const int*)d_in[7];

  char* ws=(char*)d_ws;
  size_t o=0;
  int* counts=(int*)(ws+o);      o+=(size_t)NCELL*4;
  int* offsets=(int*)(ws+o);     o+=(size_t)(NCELL+4)*4;
  int* bsum=(int*)(ws+o);        o+=(size_t)NB_SCAN*4;
  uint32_t* cellrank=(uint32_t*)(ws+o); o+=(size_t)E_IN_N*4;
  int2* sorted2=(int2*)(ws+o);   o+=(size_t)E_IN_N*8;
  ushort* wb=(ushort*)(ws+o);    o+=(size_t)36864*2;
  float* out=(float*)d_out;

  hipLaunchKernelGGL(zero_k, dim3(NCELL/1024),dim3(256),0,stream, counts);
  hipLaunchKernelGGL(hist_k, dim3(E_IN_N/256),dim3(256),0,stream, seg,succ,counts,cellrank);
  hipLaunchKernelGGL(blocksum_k, dim3(NB_SCAN),dim3(256),0,stream, counts,bsum);
  hipLaunchKernelGGL(offsets_k, dim3(NB_SCAN),dim3(256),0,stream, counts,bsum,offsets);
  hipLaunchKernelGGL(scatter_k, dim3(E_IN_N/256),dim3(256),0,stream, cellrank,dtv,offsets,sorted2);
  hipLaunchKernelGGL(wprep_k, dim3(144),dim3(256),0,stream, wk,wb);
  hipLaunchKernelGGL(compute_k, dim3(E_OUT_N/TILE_E),dim3(512),0,stream,
                     features,decay,bias,offsets,sorted2,wb,out);
}

// Round 5
// 175.198 us; speedup vs baseline: 1.7939x; 1.1997x over previous
//
#include <hip/hip_runtime.h>
#include <hip/hip_bf16.h>
#include <stdint.h>

#define E_IN_N   1048576
#define E_OUT_N  131072
#define KTAPS    9
#define CIN      64
#define COUT     64
#define NCELL    (E_OUT_N*KTAPS)   /* 1179648 */
#define NB_SCAN  1152              /* NCELL/1024 */
#define TILE_E   32
#define NKSTEP   18                /* 576/32 */

typedef __attribute__((ext_vector_type(8))) short bf16x8;
typedef __attribute__((ext_vector_type(4))) float f32x4;

__device__ __forceinline__ ushort f32_bf16(float x){
  union{float f; uint32_t u;} v; v.f=x;
  uint32_t r = v.u + 0x7FFFu + ((v.u>>16)&1u);
  return (ushort)(r>>16);
}

__global__ void zero_k(int* __restrict__ p){   // zero counts (NCELL ints)
  int i = blockIdx.x*256 + threadIdx.x;
  ((int4*)p)[i] = int4{0,0,0,0};
}

// histogram + per-event rank; cellrank = cell<<11 | rank  (cell<2^21, rank<2048)
__global__ void hist_k(const int* __restrict__ seg, const int* __restrict__ succ,
                       int* __restrict__ counts, uint32_t* __restrict__ cellrank){
  int i = blockIdx.x*256 + threadIdx.x;
  uint32_t cell = (uint32_t)(seg[i]*KTAPS + succ[i]);
  uint32_t rank = (uint32_t)atomicAdd(&counts[cell],1);
  cellrank[i] = (cell<<11) | rank;
}

__global__ void blocksum_k(const int* __restrict__ counts, int* __restrict__ bsum){
  __shared__ int sm[256];
  int b=blockIdx.x, t=threadIdx.x;
  const int4 c4 = *(const int4*)(counts + b*1024 + t*4);
  int s=c4.x+c4.y+c4.z+c4.w;
  sm[t]=s; __syncthreads();
  for(int d=128; d>0; d>>=1){ if(t<d) sm[t]+=sm[t+d]; __syncthreads(); }
  if(t==0) bsum[b]=sm[0];
}

// fused: block prefix over bsum + intra-block scan of counts -> offsets
__global__ void offsets_k(const int* __restrict__ counts, const int* __restrict__ bsum,
                          int* __restrict__ offsets){
  __shared__ int sm[256];
  int b=blockIdx.x, t=threadIdx.x;
  int s=0;
  for(int j=t; j<NB_SCAN; j+=256) if(j<b) s+=bsum[j];
  sm[t]=s; __syncthreads();
  for(int d=128; d>0; d>>=1){ if(t<d) sm[t]+=sm[t+d]; __syncthreads(); }
  int base0=sm[0]; __syncthreads();
  int base=b*1024+t*4;
  const int4 c4=*(const int4*)(counts+base);
  int s2=c4.x+c4.y+c4.z+c4.w;
  sm[t]=s2; __syncthreads();
  for(int d=1; d<256; d<<=1){ int x=(t>=d)?sm[t-d]:0; __syncthreads(); sm[t]+=x; __syncthreads(); }
  int e0v=base0 + ((t==0)?0:sm[t-1]);
  int4 o; o.x=e0v; o.y=e0v+c4.x; o.z=o.y+c4.y; o.w=o.z+c4.z;
  *(int4*)(offsets+base)=o;
  if(b==NB_SCAN-1 && t==255) offsets[NCELL]=o.w+c4.w;
}

// place events: pos = offsets[cell] + rank (no atomics); payload = idx|(cell%288)<<20, dt
__global__ void scatter_k(const uint32_t* __restrict__ cellrank, const float* __restrict__ dtv,
                          const int* __restrict__ offsets, int2* __restrict__ sorted2){
  int i=blockIdx.x*256+threadIdx.x;
  uint32_t cr=cellrank[i];
  uint32_t cell=cr>>11, rank=cr&2047u;
  int base=offsets[cell];
  float d=dtv[i];
  uint32_t x=cell>>5;
  uint32_t q=__umulhi(x,477218592u);          // /9  (exact for x<2^27)
  uint32_t rel=cell - q*288u;                 // cell % 288 (block-local)
  sorted2[base+(int)rank]=int2{(int)((uint32_t)i | (rel<<20)), __float_as_int(d)};
}

// pre-permute W[576][64] f32 -> bf16 MFMA B-fragment order: wb[((nt*18+ks)*64+lane)*8+j]
__global__ void wprep_k(const float* __restrict__ wk, ushort* __restrict__ wb){
  int slot=blockIdx.x*256+threadIdx.x;   // 36864 total
  int j=slot&7; int t2=slot>>3; int lane=t2&63; int t3=t2>>6;
  int ks=t3%NKSTEP; int nt=t3/NKSTEP;
  int r=ks*32+((lane>>4)*8)+j; int col=nt*16+(lane&15);
  wb[slot]=f32_bf16(wk[r*COUT+col]);
}

__global__ __launch_bounds__(512,4) void compute_k(
    const float* __restrict__ features, const float* __restrict__ decay,
    const float* __restrict__ bias, const int* __restrict__ offsets,
    const int2* __restrict__ sorted2, const ushort* __restrict__ wb,
    float* __restrict__ out)
{
  __shared__ ushort agg[TILE_E*584];   // 576 + 8 pad per row
  const int tid=threadIdx.x, wv=tid>>6, lane=tid&63;
  const int e0=blockIdx.x*TILE_E;
  const int cb0=e0*KTAPS;

  for(int i=tid;i<TILE_E*584/2;i+=512) ((uint32_t*)agg)[i]=0u;
  float x=decay[lane];
  float rate=fmaxf(x,0.f)+log1pf(__expf(-fabsf(x)));   // softplus
  __syncthreads();

  // ---- aggregation: wave owns 36 contiguous cells (rel in [wv*36, wv*36+36)) ----
  // Branchless scalar-driven chunks of 16 events; pads neutralized arithmetically;
  // per-cell merge via "last write wins" (same-cell events are contiguous).
  {
    const int c0=cb0+wv*36;
    int jv=0; if(lane<2) jv=offsets[c0+lane*36];
    int cb = __builtin_amdgcn_readfirstlane(__shfl(jv,0));
    const int jE = __builtin_amdgcn_readfirstlane(__shfl(jv,1));

    int prevRel=-1;
    float num=0.f, den=1.f;

    while(cb<jE){
      int qx[16]; float qd[16];
      #pragma unroll
      for(int e=0;e<16;e++){               // uniform base -> scalar loads
        int2 t=sorted2[cb+e];
        qx[e]=t.x; qd[e]=__int_as_float(t.y);
      }
      float fl[16];
      #pragma unroll
      for(int e=0;e<16;e++){               // 16 independent gathers in flight
        int iu = qx[e] & 0xFFFFF;          // idx < 2^20 == E_IN, always in-bounds
        fl[e] = features[((size_t)iu<<6) + lane];
      }
      #pragma unroll
      for(int e=0;e<16;e++){
        const int ok = (cb+e) < jE;
        int rel = (int)(((uint32_t)qx[e])>>20);
        rel = ok ? rel : prevRel;          // pad: repeat last cell (harmless rewrite)
        float w = __expf(-qd[e]*rate);
        w = ok ? w : 0.f;
        const float same = (rel==prevRel) ? 1.f : 0.f;
        num = num*same + w*fl[e];
        den = den*same + w;
        const int le=(rel*7282)>>16, kk=rel-le*9;
        agg[le*584 + kk*64 + lane] = f32_bf16(num*__builtin_amdgcn_rcpf(den));
        prevRel = rel;
      }
      cb += 16;
    }
  }
  __syncthreads();

  // ---- GEMM: wave tile = 16 rows (mt) x 16 cols (nt), K=576 ----
  const int mt=wv>>2, nt=wv&3;
  const int arow=mt*16+(lane&15);
  const int koff=(lane>>4)*8;
  const ushort* wbp = wb + ((size_t)(nt*NKSTEP)*64 + (size_t)lane)*8;
  f32x4 acc={0.f,0.f,0.f,0.f};
  #pragma unroll
  for(int ks=0;ks<NKSTEP;ks++){
    bf16x8 a=*(const bf16x8*)&agg[arow*584+ks*32+koff];
    bf16x8 bfr=*(const bf16x8*)(wbp + (size_t)ks*512);
    acc=__builtin_amdgcn_mfma_f32_16x16x32_bf16(a,bfr,acc,0,0,0);
  }
  const int orow=e0+mt*16+((lane>>4)*4);
  const int ocol=nt*16+(lane&15);
  const float bv=bias[ocol];
  #pragma unroll
  for(int r=0;r<4;r++) out[(size_t)(orow+r)*COUT+ocol]=acc[r]+bv;
}

extern "C" void kernel_launch(void* const* d_in, const int* in_sizes, int n_in,
                              void* d_out, int out_size, void* d_ws, size_t ws_size,
                              hipStream_t stream){
  const float* features=(const float*)d_in[0];
  const float* dtv=(const float*)d_in[1];
  const float* decay=(const float*)d_in[3];
  const float* wk=(const float*)d_in[4];
  const float* bias=(const float*)d_in[5];
  const int* succ=(const int*)d_in[6];
  const int* seg=(const int*)d_in[7];

  char* ws=(char*)d_ws;
  size_t o=0;
  int* counts=(int*)(ws+o);      o+=(size_t)NCELL*4;
  int* offsets=(int*)(ws+o);     o+=(size_t)(NCELL+4)*4;
  int* bsum=(int*)(ws+o);        o+=(size_t)NB_SCAN*4;
  uint32_t* cellrank=(uint32_t*)(ws+o); o+=(size_t)E_IN_N*4;
  int2* sorted2=(int2*)(ws+o);   o+=(size_t)(E_IN_N+16)*8;   // +16 slack for padded chunk reads
  ushort* wb=(ushort*)(ws+o);    o+=(size_t)36864*2;
  float* out=(float*)d_out;

  hipLaunchKernelGGL(zero_k, dim3(NCELL/1024),dim3(256),0,stream, counts);
  hipLaunchKernelGGL(hist_k, dim3(E_IN_N/256),dim3(256),0,stream, seg,succ,counts,cellrank);
  hipLaunchKernelGGL(blocksum_k, dim3(NB_SCAN),dim3(256),0,stream, counts,bsum);
  hipLaunchKernelGGL(offsets_k, dim3(NB_SCAN),dim3(256),0,stream, counts,bsum,offsets);
  hipLaunchKernelGGL(scatter_k, dim3(E_IN_N/256),dim3(256),0,stream, cellrank,dtv,offsets,sorted2);
  hipLaunchKernelGGL(wprep_k, dim3(144),dim3(256),0,stream, wk,wb);
  hipLaunchKernelGGL(compute_k, dim3(E_OUT_N/TILE_E),dim3(512),0,stream,
                     features,decay,bias,offsets,sorted2,wb,out);
}